// Round 11
// baseline (139.835 us; speedup 1.0000x reference)
//
#include <hip/hip_runtime.h>
#include <math.h>

#define N_BOXES 10647
#define NUM_CLASSES 80
#define MAX_BOXES 20
#define IOU_T 0.1f
#define SCORE_T 0.3f

#define NT 1024
#define NWAVES (NT / 64)
#define KP 11      // ceil(N_BOXES / NT): per-thread candidate slots
#define WCAP 256   // window capacity (LDS)
#define TGT 192    // target window size (expected need ~40; ~5x margin)

// Transpose tiling (kernel 1)
#define TROWS 128
#define TBLOCKS 84      // ceil(10647 / 128)
#define CPBLOCKS 6      // boxes-copy blocks
#define K1_BLOCKS (TBLOCKS + CPBLOCKS)

// Output layout (all float32, concatenated):
//   [0)      boxes copy        N_BOXES*4               = 42588
//   [42588)  scores transposed NUM_CLASSES*N_BOXES     = 851760
//   [894348) nms_final         NUM_CLASSES*MAX_BOXES*3 = 4800
#define OUT_OFF_SCORES (N_BOXES * 4)
#define OUT_OFF_NMS (N_BOXES * 4 + NUM_CLASSES * N_BOXES)

// R10 post-mortem: nms_kernel was 42.5us even on warm-cache replays
// (hbm_bytes ~20KB) -> pure serial latency, and the only 20-iteration
// serial section is the window-greedy. Its u64 shuffle butterfly = 12
// dependent ds_bpermute ops (~120cyc each) per iteration. R11 replaces the
// whole cross-lane reduce with ONE LDS atomicMax (ds_max_u64) + one
// readback atomic (DS pipe is in-order per wave), drops the FIND/ballot
// winner-location chain (index comes from the key; winner self-kills by
// key equality), and fuses next-round local max into the kill pass.
#define FOR_K(OP) OP(0) OP(1) OP(2) OP(3) OP(4) OP(5) OP(6) OP(7) OP(8) OP(9) OP(10)
#define FOR_J(OP) OP(0) OP(1) OP(2) OP(3)

// Reference-exact IoU>T test (individually rounded float32 ops; inter==0 =>
// reference IoU is 0 => not suppressed, divide skipped).
__device__ __forceinline__ bool iou_gt(float jy1, float jx1, float jy2,
                                       float jx2, float area_j, float4 b) {
    float ty = fmaxf(jy1, b.x);
    float tx = fmaxf(jx1, b.y);
    float by = fminf(jy2, b.z);
    float bx = fminf(jx2, b.w);
    float dy = fmaxf(__fsub_rn(by, ty), 0.0f);
    float dx = fmaxf(__fsub_rn(bx, tx), 0.0f);
    float inter = __fmul_rn(dy, dx);
    if (!(inter > 0.0f)) return false;
    float area_i = __fmul_rn(__fsub_rn(b.z, b.x), __fsub_rn(b.w, b.y));
    float uni = __fsub_rn(__fadd_rn(area_j, area_i), inter);
    float iou = (uni > 0.0f) ? __fdiv_rn(inter, uni) : 0.0f;
    return iou > IOU_T;
}

// ---------------------------------------------------------------------------
// Kernel 1: coalesced transpose of scores [N,C]->[C,N] into out, + boxes copy
// ---------------------------------------------------------------------------
__global__ __launch_bounds__(NT) void transpose_copy_kernel(
    const float* __restrict__ boxes, const float* __restrict__ scores,
    float* __restrict__ out) {
    const int tid = threadIdx.x;
    const int b = blockIdx.x;

    if (b >= TBLOCKS) {
        // ---- boxes copy: 10647 float4s, coalesced both sides ----
        for (int q = (b - TBLOCKS) * NT + tid; q < N_BOXES;
             q += CPBLOCKS * NT) {
            ((float4*)out)[q] = ((const float4*)boxes)[q];
        }
        return;
    }

    // ---- one 128-row x 80-col tile ----
    __shared__ float lds[TROWS * 81];  // [r][c], pad 81 -> conflict-free
    const int r0 = b * TROWS;
    const int nr = min(TROWS, N_BOXES - r0);

    // Read: contiguous chunk scores[r0*80 .. (r0+nr)*80), float4 loads.
    const int nq = nr * 20;  // 80 floats/row = 20 float4/row
    for (int q = tid; q < nq; q += NT) {
        const int r = q / 20;
        const int c4 = (q - r * 20) * 4;
        float4 v = *(const float4*)(scores + (r0 + r) * NUM_CLASSES + c4);
        float* dst = &lds[r * 81 + c4];
        dst[0] = v.x;
        dst[1] = v.y;
        dst[2] = v.z;
        dst[3] = v.w;
    }
    __syncthreads();

    // Write: for each class, 128 consecutive elements of the [C,N] column.
    const int r = tid & (TROWS - 1);
    const int chi = tid >> 7;  // 0..7
    if (r < nr) {
        #pragma unroll
        for (int p = 0; p < 10; ++p) {
            const int c = p * 8 + chi;
            out[OUT_OFF_SCORES + c * N_BOXES + r0 + r] = lds[r * 81 + c];
        }
    }
}

// ---------------------------------------------------------------------------
// Kernel 2: per-class NMS (reads coalesced transposed scores from out)
// ---------------------------------------------------------------------------
__global__ __launch_bounds__(NT) void nms_kernel(
    const float* __restrict__ boxes, float* __restrict__ out) {
    const int tid = threadIdx.x;
    const int c = blockIdx.x;
    const int wave = tid >> 6;
    const int lane = tid & 63;
    const float4* boxes4 = (const float4*)boxes;
    const float* col = out + OUT_OFF_SCORES + c * N_BOXES;  // contiguous

    __shared__ int s_hist[2048];                    // 8 KB
    __shared__ unsigned long long s_k[WCAP];        // 2 KB window keys
    __shared__ float4 s_b4[WCAP];                   // 4 KB window boxes
    __shared__ unsigned long long s_rk[2][NWAVES];  // fallback reduce
    __shared__ unsigned long long s_amax[2];        // Phase D atomic-max slots
    __shared__ int s_out[MAX_BOXES];
    __shared__ int s_bstar, s_total, s_cnt, s_nsel;

    if (tid < MAX_BOXES) s_out[tid] = -1;
    if (tid == 0) { s_cnt = 0; s_nsel = 0; }
    if (tid < 2) s_amax[tid] = 0;
    s_hist[tid] = 0;
    s_hist[tid + NT] = 0;
    __syncthreads();

    // ---- Phase A: coalesced column read -> keys + histogram.
    // key = (score_bits << 32) | (0xFFFFFFFF - idx): u64 max == max score,
    // tie -> lowest index (jnp.argmax first-occurrence). 0 = invalid.
#define DECL_K(k) unsigned long long k_##k = 0;
    FOR_K(DECL_K)
#undef DECL_K
#define BUILD_K(k)                                                     \
    {                                                                  \
        int i = tid + (k)*NT;                                          \
        if (i < N_BOXES) {                                             \
            float v = col[i];                                          \
            if (v >= SCORE_T) {                                        \
                unsigned int vb = __float_as_uint(v);                  \
                k_##k = ((unsigned long long)vb << 32) |               \
                        (0xFFFFFFFFu - (unsigned int)i);               \
                atomicAdd(&s_hist[(vb - 0x3E800000u) >> 13], 1);       \
            }                                                          \
        }                                                              \
    }
    FOR_K(BUILD_K)
#undef BUILD_K
    __syncthreads();

    // ---- Phase B (wave 0, fully parallel): b* = max bin with
    // suffix-count >= TGT (0 if total < TGT).
    if (wave == 0) {
        int lsum = 0;
        #pragma unroll
        for (int t = 0; t < 32; ++t) {
            int bb = (t + lane) & 31;  // rotate -> conflict-free banks
            lsum += s_hist[lane * 32 + bb];
        }
        int S = lsum;  // inclusive suffix over lanes (lane l: bins >= l*32)
        #pragma unroll
        for (int off = 1; off < 64; off <<= 1) {
            int up = __shfl_down(S, off);
            if (lane + off < 64) S += up;
        }
        unsigned long long mk = __ballot(S >= TGT);
        int bstar = 0;
        if (mk != 0) {
            const int L = 63 - __builtin_clzll(mk);
            const int S_L = __shfl(S, L);
            const int lsum_L = __shfl(lsum, L);
            const int S_above = S_L - lsum_L;  // suffix above lane L's bins
            int h = (lane < 32) ? s_hist[L * 32 + lane] : 0;
            int sfx = h;
            #pragma unroll
            for (int off = 1; off < 64; off <<= 1) {
                int up = __shfl_down(sfx, off);
                if (lane + off < 64) sfx += up;
            }
            unsigned long long sel = __ballot(sfx + S_above >= TGT);
            bstar = L * 32 + (63 - __builtin_clzll(sel));
        }
        if (lane == 0) {
            s_bstar = bstar;
            s_total = S;  // lane0 inclusive suffix == grand total
        }
    }
    __syncthreads();

    const unsigned int tbits = 0x3E800000u + ((unsigned int)s_bstar << 13);

    // ---- Phase C: compact window (score_bits >= tbits) into LDS ----
#define COMPACT_K(k)                                                    \
    {                                                                   \
        bool p = (k_##k != 0) &&                                        \
                 ((unsigned int)(k_##k >> 32) >= tbits);                \
        unsigned long long m = __ballot(p);                             \
        int basew = 0;                                                  \
        if (lane == 0 && m) basew = atomicAdd(&s_cnt, __popcll(m));     \
        basew = __shfl(basew, 0);                                       \
        if (p) {                                                        \
            int pos = basew + __popcll(m & ((1ull << lane) - 1ull));    \
            if (pos < WCAP) {                                           \
                s_k[pos] = k_##k;                                       \
                s_b4[pos] = boxes4[0xFFFFFFFFu - (unsigned int)k_##k];  \
            }                                                           \
        }                                                               \
    }
    FOR_K(COMPACT_K)
#undef COMPACT_K
    __syncthreads();

    const int wcnt = s_cnt;
    const bool overflow = (wcnt > WCAP);  // pathological ties only

    // ---- Phase D: wave-0-only greedy on the window. Cross-lane reduce is
    // ONE ds_max_u64 + one readback atomic (in-order DS pipe), not a
    // 12-deep bpermute butterfly. Winner located by key, not by search.
    if (wave == 0 && !overflow) {
#define DECL_J(j) unsigned long long w_##j = 0;
        FOR_J(DECL_J)
#undef DECL_J
#define LOADW_J(j)                                             \
        { int i = lane + 64 * (j); if (i < wcnt) w_##j = s_k[i]; }
        FOR_J(LOADW_J)
#undef LOADW_J
        unsigned long long lmax = 0;
#define LMAX_J(j) if (w_##j > lmax) lmax = w_##j;
        FOR_J(LMAX_J)
#undef LMAX_J
        int nsel = 0;
        for (int sel = 0; sel < MAX_BOXES; ++sel) {
            const int par = sel & 1;
            atomicMax(&s_amax[par], lmax);            // 1 instr, all lanes
            unsigned long long bk = atomicMax(&s_amax[par], 0ull);  // settled
            if (lane == 0) s_amax[par] = 0;           // reset for sel+2
            if (bk == 0) break;                       // wave-uniform
            const int widx = (int)(0xFFFFFFFFu - (unsigned int)bk);
            if (lane == 0) s_out[nsel] = widx;
            float4 wb = boxes4[widx];  // uniform fetch; L1-warm (Phase C)
            const float area_j =
                __fmul_rn(__fsub_rn(wb.z, wb.x), __fsub_rn(wb.w, wb.y));
            lmax = 0;
            // kill pass fused with next-round local max; winner self-kills
            // by key equality (keys unique).
#define KILL_J(j)                                                       \
            if (w_##j != 0) {                                           \
                if (w_##j == bk) {                                      \
                    w_##j = 0;                                          \
                } else {                                                \
                    float4 b = s_b4[lane + 64 * (j)];                   \
                    if (iou_gt(wb.x, wb.y, wb.z, wb.w, area_j, b))      \
                        w_##j = 0;                                      \
                }                                                       \
                if (w_##j > lmax) lmax = w_##j;                         \
            }
            FOR_J(KILL_J)
#undef KILL_J
            ++nsel;
        }
        if (lane == 0) s_nsel = nsel;
    }
    __syncthreads();

    // ---- Phase E: exact fallback (window exhausted early / overflow) ----
    const int nsel0 = s_nsel;
    const bool needs_more =
        (nsel0 < MAX_BOXES) && (overflow || (wcnt < s_total));
    if (needs_more) {
#define LIVE_K(k)                                                        \
        if (k_##k != 0) {                                                \
            bool dead =                                                  \
                (!overflow &&                                            \
                 ((unsigned int)(k_##k >> 32) >= tbits));                \
            if (!dead && nsel0 > 0) {                                    \
                int i = tid + (k)*NT;                                    \
                float4 bi = boxes4[i];                                   \
                for (int j = 0; j < nsel0; ++j) {                        \
                    float4 sb = boxes4[s_out[j]];                        \
                    float aj = __fmul_rn(__fsub_rn(sb.z, sb.x),          \
                                         __fsub_rn(sb.w, sb.y));         \
                    if (iou_gt(sb.x, sb.y, sb.z, sb.w, aj, bi)) {        \
                        dead = true;                                     \
                        break;                                           \
                    }                                                    \
                }                                                        \
            }                                                            \
            if (dead) k_##k = 0;                                         \
        }
        FOR_K(LIVE_K)
#undef LIVE_K
        for (int slot = nsel0; slot < MAX_BOXES; ++slot) {
            unsigned long long bk = 0;
#define MAXK_K(k) if (k_##k > bk) bk = k_##k;
            FOR_K(MAXK_K)
#undef MAXK_K
            #pragma unroll
            for (int off = 32; off >= 1; off >>= 1) {
                unsigned long long o =
                    (unsigned long long)__shfl_xor((long long)bk, off);
                if (o > bk) bk = o;
            }
            const int par = slot & 1;
            if (lane == 0) s_rk[par][wave] = bk;
            __syncthreads();
            unsigned long long f = s_rk[par][0];
            #pragma unroll
            for (int w = 1; w < NWAVES; ++w) {
                unsigned long long o = s_rk[par][w];
                if (o > f) f = o;
            }
            if (f == 0) break;  // uniform
            const int widx = (int)(0xFFFFFFFFu - (unsigned int)f);
            if (tid == 0) s_out[slot] = widx;
            float4 wb = boxes4[widx];  // uniform L1 broadcast
            const float area_j =
                __fmul_rn(__fsub_rn(wb.z, wb.x), __fsub_rn(wb.w, wb.y));
#define SCANE_K(k)                                                      \
            if (k_##k != 0) {                                           \
                int i = tid + (k)*NT;                                   \
                float4 b = boxes4[i];                                   \
                if (i == widx ||                                        \
                    iou_gt(wb.x, wb.y, wb.z, wb.w, area_j, b))          \
                    k_##k = 0;                                          \
            }
            FOR_K(SCANE_K)
#undef SCANE_K
        }
    }

    // ---- emit rows ----
    __syncthreads();
    if (tid < MAX_BOXES) {
        int bi = s_out[tid];
        int o = OUT_OFF_NMS + c * MAX_BOXES * 3 + tid * 3;
        if (bi >= 0) {
            out[o + 0] = 0.0f;
            out[o + 1] = (float)c;
            out[o + 2] = (float)bi;
        } else {
            out[o + 0] = -1.0f;
            out[o + 1] = -1.0f;
            out[o + 2] = -1.0f;
        }
    }
}

extern "C" void kernel_launch(void* const* d_in, const int* in_sizes, int n_in,
                              void* d_out, int out_size, void* d_ws,
                              size_t ws_size, hipStream_t stream) {
    const float* boxes = (const float*)d_in[0];   // [N,4] fp32
    const float* scores = (const float*)d_in[1];  // [N,C] fp32
    float* out = (float*)d_out;

    // Launch 1: coalesced transpose (+ boxes copy) into out.
    transpose_copy_kernel<<<K1_BLOCKS, NT, 0, stream>>>(boxes, scores, out);
    // Launch 2: NMS reads the transposed columns contiguously.
    nms_kernel<<<NUM_CLASSES, NT, 0, stream>>>(boxes, out);
}

// Round 12
// 78.717 us; speedup vs baseline: 1.7764x; 1.7764x over previous
//
#include <hip/hip_runtime.h>
#include <math.h>

#define N_BOXES 10647
#define NUM_CLASSES 80
#define MAX_BOXES 20
#define IOU_T 0.1f
#define SCORE_T 0.3f

#define NT 1024
#define NWAVES (NT / 64)
#define KP 11      // ceil(N_BOXES / NT): per-thread candidate slots
#define WCAP 128   // window capacity (LDS)
#define TGT 96     // target window size (expected examine ~40 for 20 keeps)

// Transpose tiling (kernel 1)
#define TROWS 128
#define TBLOCKS 84      // ceil(10647 / 128)
#define CPBLOCKS 6      // boxes-copy blocks
#define K1_BLOCKS (TBLOCKS + CPBLOCKS)

// Output layout (all float32, concatenated):
//   [0)      boxes copy        N_BOXES*4               = 42588
//   [42588)  scores transposed NUM_CLASSES*N_BOXES     = 851760
//   [894348) nms_final         NUM_CLASSES*MAX_BOXES*3 = 4800
#define OUT_OFF_SCORES (N_BOXES * 4)
#define OUT_OFF_NMS (N_BOXES * 4 + NUM_CLASSES * N_BOXES)

// R11 post-mortem: same-address LDS atomicMax x64 lanes serializes in the
// DS pipe (~4k cyc/iter) -> 81us, worse than the butterfly (42.5us). R12
// removes the per-selection argmax ENTIRELY: greedy NMS processed in
// (score desc, idx asc) order == keep iff IoU<=T vs previously KEPT boxes.
// So: rank-sort the ~96-candidate window once (parallel O(n^2) rank pass,
// no shuffle chains), then ONE wave walks the sorted list with kept boxes
// in per-lane registers (serial chain per candidate = broadcast LDS read +
// <=20 lane-parallel IoUs + one ballot). No per-step kill passes.
#define FOR_K(OP) OP(0) OP(1) OP(2) OP(3) OP(4) OP(5) OP(6) OP(7) OP(8) OP(9) OP(10)

// Reference-exact IoU>T test (individually rounded float32 ops; inter==0 =>
// reference IoU is 0 => not suppressed, divide skipped).
__device__ __forceinline__ bool iou_gt(float jy1, float jx1, float jy2,
                                       float jx2, float area_j, float4 b) {
    float ty = fmaxf(jy1, b.x);
    float tx = fmaxf(jx1, b.y);
    float by = fminf(jy2, b.z);
    float bx = fminf(jx2, b.w);
    float dy = fmaxf(__fsub_rn(by, ty), 0.0f);
    float dx = fmaxf(__fsub_rn(bx, tx), 0.0f);
    float inter = __fmul_rn(dy, dx);
    if (!(inter > 0.0f)) return false;
    float area_i = __fmul_rn(__fsub_rn(b.z, b.x), __fsub_rn(b.w, b.y));
    float uni = __fsub_rn(__fadd_rn(area_j, area_i), inter);
    float iou = (uni > 0.0f) ? __fdiv_rn(inter, uni) : 0.0f;
    return iou > IOU_T;
}

// ---------------------------------------------------------------------------
// Kernel 1: coalesced transpose of scores [N,C]->[C,N] into out, + boxes copy
// ---------------------------------------------------------------------------
__global__ __launch_bounds__(NT) void transpose_copy_kernel(
    const float* __restrict__ boxes, const float* __restrict__ scores,
    float* __restrict__ out) {
    const int tid = threadIdx.x;
    const int b = blockIdx.x;

    if (b >= TBLOCKS) {
        // ---- boxes copy: 10647 float4s, coalesced both sides ----
        for (int q = (b - TBLOCKS) * NT + tid; q < N_BOXES;
             q += CPBLOCKS * NT) {
            ((float4*)out)[q] = ((const float4*)boxes)[q];
        }
        return;
    }

    // ---- one 128-row x 80-col tile ----
    __shared__ float lds[TROWS * 81];  // [r][c], pad 81 -> conflict-free
    const int r0 = b * TROWS;
    const int nr = min(TROWS, N_BOXES - r0);

    // Read: contiguous chunk scores[r0*80 .. (r0+nr)*80), float4 loads.
    const int nq = nr * 20;  // 80 floats/row = 20 float4/row
    for (int q = tid; q < nq; q += NT) {
        const int r = q / 20;
        const int c4 = (q - r * 20) * 4;
        float4 v = *(const float4*)(scores + (r0 + r) * NUM_CLASSES + c4);
        float* dst = &lds[r * 81 + c4];
        dst[0] = v.x;
        dst[1] = v.y;
        dst[2] = v.z;
        dst[3] = v.w;
    }
    __syncthreads();

    // Write: for each class, 128 consecutive elements of the [C,N] column.
    const int r = tid & (TROWS - 1);
    const int chi = tid >> 7;  // 0..7
    if (r < nr) {
        #pragma unroll
        for (int p = 0; p < 10; ++p) {
            const int c = p * 8 + chi;
            out[OUT_OFF_SCORES + c * N_BOXES + r0 + r] = lds[r * 81 + c];
        }
    }
}

// ---------------------------------------------------------------------------
// Kernel 2: per-class NMS (reads coalesced transposed scores from out)
// ---------------------------------------------------------------------------
__global__ __launch_bounds__(NT) void nms_kernel(
    const float* __restrict__ boxes, float* __restrict__ out) {
    const int tid = threadIdx.x;
    const int c = blockIdx.x;
    const int wave = tid >> 6;
    const int lane = tid & 63;
    const float4* boxes4 = (const float4*)boxes;
    const float* col = out + OUT_OFF_SCORES + c * N_BOXES;  // contiguous

    __shared__ int s_hist[2048];                    // 8 KB
    __shared__ unsigned long long s_k[WCAP];        // 1 KB window keys
    __shared__ float4 s_b4[WCAP];                   // 2 KB window boxes
    __shared__ unsigned long long s_ks[WCAP];       // 1 KB sorted keys
    __shared__ float4 s_bs[WCAP];                   // 2 KB sorted boxes
    __shared__ unsigned long long s_rk[2][NWAVES];  // fallback reduce
    __shared__ int s_out[MAX_BOXES];
    __shared__ int s_bstar, s_total, s_cnt, s_nsel;

    if (tid < MAX_BOXES) s_out[tid] = -1;
    if (tid == 0) { s_cnt = 0; s_nsel = 0; }
    s_hist[tid] = 0;
    s_hist[tid + NT] = 0;
    __syncthreads();

    // ---- Phase A: coalesced column read -> keys + histogram.
    // key = (score_bits << 32) | (0xFFFFFFFF - idx): u64 max == max score,
    // tie -> lowest index (jnp.argmax first-occurrence). 0 = invalid.
#define DECL_K(k) unsigned long long k_##k = 0;
    FOR_K(DECL_K)
#undef DECL_K
#define BUILD_K(k)                                                     \
    {                                                                  \
        int i = tid + (k)*NT;                                          \
        if (i < N_BOXES) {                                             \
            float v = col[i];                                          \
            if (v >= SCORE_T) {                                        \
                unsigned int vb = __float_as_uint(v);                  \
                k_##k = ((unsigned long long)vb << 32) |               \
                        (0xFFFFFFFFu - (unsigned int)i);               \
                atomicAdd(&s_hist[(vb - 0x3E800000u) >> 13], 1);       \
            }                                                          \
        }                                                              \
    }
    FOR_K(BUILD_K)
#undef BUILD_K
    __syncthreads();

    // ---- Phase B (wave 0, fully parallel): b* = max bin with
    // suffix-count >= TGT (0 if total < TGT).
    if (wave == 0) {
        int lsum = 0;
        #pragma unroll
        for (int t = 0; t < 32; ++t) {
            int bb = (t + lane) & 31;  // rotate -> conflict-free banks
            lsum += s_hist[lane * 32 + bb];
        }
        int S = lsum;  // inclusive suffix over lanes (lane l: bins >= l*32)
        #pragma unroll
        for (int off = 1; off < 64; off <<= 1) {
            int up = __shfl_down(S, off);
            if (lane + off < 64) S += up;
        }
        unsigned long long mk = __ballot(S >= TGT);
        int bstar = 0;
        if (mk != 0) {
            const int L = 63 - __builtin_clzll(mk);
            const int S_L = __shfl(S, L);
            const int lsum_L = __shfl(lsum, L);
            const int S_above = S_L - lsum_L;  // suffix above lane L's bins
            int h = (lane < 32) ? s_hist[L * 32 + lane] : 0;
            int sfx = h;
            #pragma unroll
            for (int off = 1; off < 64; off <<= 1) {
                int up = __shfl_down(sfx, off);
                if (lane + off < 64) sfx += up;
            }
            unsigned long long sel = __ballot(sfx + S_above >= TGT);
            bstar = L * 32 + (63 - __builtin_clzll(sel));
        }
        if (lane == 0) {
            s_bstar = bstar;
            s_total = S;  // lane0 inclusive suffix == grand total
        }
    }
    __syncthreads();

    const unsigned int tbits = 0x3E800000u + ((unsigned int)s_bstar << 13);

    // ---- Phase C: compact window (score_bits >= tbits) into LDS ----
#define COMPACT_K(k)                                                    \
    {                                                                   \
        bool p = (k_##k != 0) &&                                        \
                 ((unsigned int)(k_##k >> 32) >= tbits);                \
        unsigned long long m = __ballot(p);                             \
        int basew = 0;                                                  \
        if (lane == 0 && m) basew = atomicAdd(&s_cnt, __popcll(m));     \
        basew = __shfl(basew, 0);                                       \
        if (p) {                                                        \
            int pos = basew + __popcll(m & ((1ull << lane) - 1ull));    \
            if (pos < WCAP) {                                           \
                s_k[pos] = k_##k;                                       \
                s_b4[pos] = boxes4[0xFFFFFFFFu - (unsigned int)k_##k];  \
            }                                                           \
        }                                                               \
    }
    FOR_K(COMPACT_K)
#undef COMPACT_K
    __syncthreads();

    const int wcnt = s_cnt;
    const bool overflow = (wcnt > WCAP);  // pathological ties only

    // ---- Phase D1: parallel rank sort of the window (threads 0..wcnt).
    // rank_i = #{j : key_j > key_i}; keys unique -> permutation. All lanes
    // of a wave read the same s_k[j] per step -> broadcast, conflict-free.
    if (!overflow && tid < wcnt) {
        const unsigned long long mykey = s_k[tid];
        const float4 mybox = s_b4[tid];
        int rank = 0;
        for (int j = 0; j < wcnt; ++j) rank += (s_k[j] > mykey) ? 1 : 0;
        s_ks[rank] = mykey;
        s_bs[rank] = mybox;
    }
    __syncthreads();

    // ---- Phase D2: wave-0 sorted walk. Kept boxes one-per-lane in regs.
    // Per candidate: broadcast LDS read (prefetched) + <=20 parallel IoUs
    // + one ballot. No argmax, no kill passes.
    if (wave == 0 && !overflow && wcnt > 0) {
        int nkept = 0;
        float ky1 = 0.f, kx1 = 0.f, ky2 = 0.f, kx2 = 0.f, karea = 0.f;
        float4 bc = s_bs[0];
        unsigned long long kc = s_ks[0];
        for (int r = 0; r < wcnt; ++r) {
            const int rn = (r + 1 < wcnt) ? r + 1 : r;
            float4 bn = s_bs[rn];           // prefetch next (independent)
            unsigned long long kn = s_ks[rn];
            bool sup = (lane < nkept) &&
                       iou_gt(ky1, kx1, ky2, kx2, karea, bc);
            if (__ballot(sup) == 0) {
                if (lane == nkept) {
                    ky1 = bc.x;
                    kx1 = bc.y;
                    ky2 = bc.z;
                    kx2 = bc.w;
                    // Same op order as the reference's area1.
                    karea = __fmul_rn(__fsub_rn(bc.z, bc.x),
                                      __fsub_rn(bc.w, bc.y));
                }
                if (lane == 0)
                    s_out[nkept] = (int)(0xFFFFFFFFu - (unsigned int)kc);
                ++nkept;
                if (nkept == MAX_BOXES) break;
            }
            bc = bn;
            kc = kn;
        }
        if (lane == 0) s_nsel = nkept;
    }
    __syncthreads();

    // ---- Phase E: exact fallback (window exhausted early / overflow).
    // Invariant: if !overflow and nsel0 < 20, every window member was
    // examined (kept or suppressed) -> all dead; non-members re-checked
    // against the selected set. Never triggers on typical data.
    const int nsel0 = s_nsel;
    const bool needs_more =
        (nsel0 < MAX_BOXES) && (overflow || (wcnt < s_total));
    if (needs_more) {
#define LIVE_K(k)                                                        \
        if (k_##k != 0) {                                                \
            bool dead =                                                  \
                (!overflow &&                                            \
                 ((unsigned int)(k_##k >> 32) >= tbits));                \
            if (!dead && nsel0 > 0) {                                    \
                int i = tid + (k)*NT;                                    \
                float4 bi = boxes4[i];                                   \
                for (int j = 0; j < nsel0; ++j) {                        \
                    float4 sb = boxes4[s_out[j]];                        \
                    float aj = __fmul_rn(__fsub_rn(sb.z, sb.x),          \
                                         __fsub_rn(sb.w, sb.y));         \
                    if (iou_gt(sb.x, sb.y, sb.z, sb.w, aj, bi)) {        \
                        dead = true;                                     \
                        break;                                           \
                    }                                                    \
                }                                                        \
            }                                                            \
            if (dead) k_##k = 0;                                         \
        }
        FOR_K(LIVE_K)
#undef LIVE_K
        for (int slot = nsel0; slot < MAX_BOXES; ++slot) {
            unsigned long long bk = 0;
#define MAXK_K(k) if (k_##k > bk) bk = k_##k;
            FOR_K(MAXK_K)
#undef MAXK_K
            #pragma unroll
            for (int off = 32; off >= 1; off >>= 1) {
                unsigned long long o =
                    (unsigned long long)__shfl_xor((long long)bk, off);
                if (o > bk) bk = o;
            }
            const int par = slot & 1;
            if (lane == 0) s_rk[par][wave] = bk;
            __syncthreads();
            unsigned long long f = s_rk[par][0];
            #pragma unroll
            for (int w = 1; w < NWAVES; ++w) {
                unsigned long long o = s_rk[par][w];
                if (o > f) f = o;
            }
            if (f == 0) break;  // uniform
            const int widx = (int)(0xFFFFFFFFu - (unsigned int)f);
            if (tid == 0) s_out[slot] = widx;
            float4 wb = boxes4[widx];  // uniform L1 broadcast
            const float area_j =
                __fmul_rn(__fsub_rn(wb.z, wb.x), __fsub_rn(wb.w, wb.y));
#define SCANE_K(k)                                                      \
            if (k_##k != 0) {                                           \
                int i = tid + (k)*NT;                                   \
                float4 b = boxes4[i];                                   \
                if (i == widx ||                                        \
                    iou_gt(wb.x, wb.y, wb.z, wb.w, area_j, b))          \
                    k_##k = 0;                                          \
            }
            FOR_K(SCANE_K)
#undef SCANE_K
        }
    }

    // ---- emit rows ----
    __syncthreads();
    if (tid < MAX_BOXES) {
        int bi = s_out[tid];
        int o = OUT_OFF_NMS + c * MAX_BOXES * 3 + tid * 3;
        if (bi >= 0) {
            out[o + 0] = 0.0f;
            out[o + 1] = (float)c;
            out[o + 2] = (float)bi;
        } else {
            out[o + 0] = -1.0f;
            out[o + 1] = -1.0f;
            out[o + 2] = -1.0f;
        }
    }
}

extern "C" void kernel_launch(void* const* d_in, const int* in_sizes, int n_in,
                              void* d_out, int out_size, void* d_ws,
                              size_t ws_size, hipStream_t stream) {
    const float* boxes = (const float*)d_in[0];   // [N,4] fp32
    const float* scores = (const float*)d_in[1];  // [N,C] fp32
    float* out = (float*)d_out;

    // Launch 1: coalesced transpose (+ boxes copy) into out.
    transpose_copy_kernel<<<K1_BLOCKS, NT, 0, stream>>>(boxes, scores, out);
    // Launch 2: NMS reads the transposed columns contiguously.
    nms_kernel<<<NUM_CLASSES, NT, 0, stream>>>(boxes, out);
}

// Round 13
// 77.605 us; speedup vs baseline: 1.8019x; 1.0143x over previous
//
#include <hip/hip_runtime.h>
#include <math.h>

#define N_BOXES 10647
#define NUM_CLASSES 80
#define MAX_BOXES 20
#define IOU_T 0.1f
#define SCORE_T 0.3f

#define NT 1024
#define NWAVES (NT / 64)
#define KP 11      // ceil(N_BOXES / NT): per-thread candidate slots
#define WCAP 128   // window capacity (LDS)
#define TGT 96     // target window size (expected examine ~40 for 20 keeps)

// Transpose tiling (kernel 1): 64-row tiles -> 167 blocks (2x CU coverage
// vs 128-row tiles; k1 is latency-bound, not BW-bound).
#define TROWS 64
#define TBLOCKS 167     // ceil(10647 / 64)
#define CPBLOCKS 6      // boxes-copy blocks
#define K1_BLOCKS (TBLOCKS + CPBLOCKS)

// Output layout (all float32, concatenated):
//   [0)      boxes copy        N_BOXES*4               = 42588
//   [42588)  scores transposed NUM_CLASSES*N_BOXES     = 851760
//   [894348) nms_final         NUM_CLASSES*MAX_BOXES*3 = 4800
#define OUT_OFF_SCORES (N_BOXES * 4)
#define OUT_OFF_NMS (N_BOXES * 4 + NUM_CLASSES * N_BOXES)

// R12 post-mortem: sorted-walk removed the argmax; kernels fell below the
// harness's own 40us poison-fills. R13 removes D2's remaining serial
// LDS+ballot chain (~200cyc x ~40-96 candidates) with the suppression-
// bitmask scheme: IoU bit-matrix built fully in parallel (one ballot per
// row-chunk task), then a serial resolve that is pure bit-ops + one
// broadcast ds_read_b128 per kept box (~20 iterations).
#define FOR_K(OP) OP(0) OP(1) OP(2) OP(3) OP(4) OP(5) OP(6) OP(7) OP(8) OP(9) OP(10)

// Reference-exact IoU>T test (individually rounded float32 ops; inter==0 =>
// reference IoU is 0 => not suppressed, divide skipped). First box is the
// SELECTED box (reference's area1 = selected's area, added first).
__device__ __forceinline__ bool iou_gt(float jy1, float jx1, float jy2,
                                       float jx2, float area_j, float4 b) {
    float ty = fmaxf(jy1, b.x);
    float tx = fmaxf(jx1, b.y);
    float by = fminf(jy2, b.z);
    float bx = fminf(jx2, b.w);
    float dy = fmaxf(__fsub_rn(by, ty), 0.0f);
    float dx = fmaxf(__fsub_rn(bx, tx), 0.0f);
    float inter = __fmul_rn(dy, dx);
    if (!(inter > 0.0f)) return false;
    float area_i = __fmul_rn(__fsub_rn(b.z, b.x), __fsub_rn(b.w, b.y));
    float uni = __fsub_rn(__fadd_rn(area_j, area_i), inter);
    float iou = (uni > 0.0f) ? __fdiv_rn(inter, uni) : 0.0f;
    return iou > IOU_T;
}

// ---------------------------------------------------------------------------
// Kernel 1: coalesced transpose of scores [N,C]->[C,N] into out, + boxes copy
// ---------------------------------------------------------------------------
__global__ __launch_bounds__(NT) void transpose_copy_kernel(
    const float* __restrict__ boxes, const float* __restrict__ scores,
    float* __restrict__ out) {
    const int tid = threadIdx.x;
    const int b = blockIdx.x;

    if (b >= TBLOCKS) {
        // ---- boxes copy: 10647 float4s, coalesced both sides ----
        for (int q = (b - TBLOCKS) * NT + tid; q < N_BOXES;
             q += CPBLOCKS * NT) {
            ((float4*)out)[q] = ((const float4*)boxes)[q];
        }
        return;
    }

    // ---- one 64-row x 80-col tile ----
    __shared__ float lds[TROWS * 81];  // [r][c], pad 81 -> conflict-free
    const int r0 = b * TROWS;
    const int nr = min(TROWS, N_BOXES - r0);

    // Read: contiguous chunk scores[r0*80 .. (r0+nr)*80), float4 loads.
    const int nq = nr * 20;  // 80 floats/row = 20 float4/row
    for (int q = tid; q < nq; q += NT) {
        const int r = q / 20;
        const int c4 = (q - r * 20) * 4;
        float4 v = *(const float4*)(scores + (r0 + r) * NUM_CLASSES + c4);
        float* dst = &lds[r * 81 + c4];
        dst[0] = v.x;
        dst[1] = v.y;
        dst[2] = v.z;
        dst[3] = v.w;
    }
    __syncthreads();

    // Write: each wave writes 64 consecutive rows of one class (256 B
    // contiguous per store instruction), 5 classes per thread.
    const int r = tid & (TROWS - 1);
    const int chi = tid >> 6;  // 0..15
    if (r < nr) {
        #pragma unroll
        for (int p = 0; p < 5; ++p) {
            const int c = p * 16 + chi;
            out[OUT_OFF_SCORES + c * N_BOXES + r0 + r] = lds[r * 81 + c];
        }
    }
}

// ---------------------------------------------------------------------------
// Kernel 2: per-class NMS (reads coalesced transposed scores from out)
// ---------------------------------------------------------------------------
__global__ __launch_bounds__(NT) void nms_kernel(
    const float* __restrict__ boxes, float* __restrict__ out) {
    const int tid = threadIdx.x;
    const int c = blockIdx.x;
    const int wave = tid >> 6;
    const int lane = tid & 63;
    const float4* boxes4 = (const float4*)boxes;
    const float* col = out + OUT_OFF_SCORES + c * N_BOXES;  // contiguous

    __shared__ int s_hist[2048];                    // 8 KB
    __shared__ unsigned long long s_k[WCAP];        // 1 KB window keys
    __shared__ float4 s_b4[WCAP];                   // 2 KB window boxes
    __shared__ unsigned long long s_ks[WCAP];       // 1 KB sorted keys
    __shared__ float4 s_bs[WCAP];                   // 2 KB sorted boxes
    __shared__ __align__(16) unsigned long long s_mask[WCAP][2];  // 2 KB
    __shared__ unsigned long long s_rk[2][NWAVES];  // fallback reduce
    __shared__ int s_out[MAX_BOXES];
    __shared__ int s_bstar, s_total, s_cnt, s_nsel;

    if (tid < MAX_BOXES) s_out[tid] = -1;
    if (tid == 0) { s_cnt = 0; s_nsel = 0; }
    s_hist[tid] = 0;
    s_hist[tid + NT] = 0;
    __syncthreads();

    // ---- Phase A: coalesced column read -> keys + histogram.
    // key = (score_bits << 32) | (0xFFFFFFFF - idx): u64 max == max score,
    // tie -> lowest index (jnp.argmax first-occurrence). 0 = invalid.
#define DECL_K(k) unsigned long long k_##k = 0;
    FOR_K(DECL_K)
#undef DECL_K
#define BUILD_K(k)                                                     \
    {                                                                  \
        int i = tid + (k)*NT;                                          \
        if (i < N_BOXES) {                                             \
            float v = col[i];                                          \
            if (v >= SCORE_T) {                                        \
                unsigned int vb = __float_as_uint(v);                  \
                k_##k = ((unsigned long long)vb << 32) |               \
                        (0xFFFFFFFFu - (unsigned int)i);               \
                atomicAdd(&s_hist[(vb - 0x3E800000u) >> 13], 1);       \
            }                                                          \
        }                                                              \
    }
    FOR_K(BUILD_K)
#undef BUILD_K
    __syncthreads();

    // ---- Phase B (wave 0, fully parallel): b* = max bin with
    // suffix-count >= TGT (0 if total < TGT).
    if (wave == 0) {
        int lsum = 0;
        #pragma unroll
        for (int t = 0; t < 32; ++t) {
            int bb = (t + lane) & 31;  // rotate -> conflict-free banks
            lsum += s_hist[lane * 32 + bb];
        }
        int S = lsum;  // inclusive suffix over lanes (lane l: bins >= l*32)
        #pragma unroll
        for (int off = 1; off < 64; off <<= 1) {
            int up = __shfl_down(S, off);
            if (lane + off < 64) S += up;
        }
        unsigned long long mk = __ballot(S >= TGT);
        int bstar = 0;
        if (mk != 0) {
            const int L = 63 - __builtin_clzll(mk);
            const int S_L = __shfl(S, L);
            const int lsum_L = __shfl(lsum, L);
            const int S_above = S_L - lsum_L;  // suffix above lane L's bins
            int h = (lane < 32) ? s_hist[L * 32 + lane] : 0;
            int sfx = h;
            #pragma unroll
            for (int off = 1; off < 64; off <<= 1) {
                int up = __shfl_down(sfx, off);
                if (lane + off < 64) sfx += up;
            }
            unsigned long long sel = __ballot(sfx + S_above >= TGT);
            bstar = L * 32 + (63 - __builtin_clzll(sel));
        }
        if (lane == 0) {
            s_bstar = bstar;
            s_total = S;  // lane0 inclusive suffix == grand total
        }
    }
    __syncthreads();

    const unsigned int tbits = 0x3E800000u + ((unsigned int)s_bstar << 13);

    // ---- Phase C: compact window (score_bits >= tbits) into LDS ----
#define COMPACT_K(k)                                                    \
    {                                                                   \
        bool p = (k_##k != 0) &&                                        \
                 ((unsigned int)(k_##k >> 32) >= tbits);                \
        unsigned long long m = __ballot(p);                             \
        int basew = 0;                                                  \
        if (lane == 0 && m) basew = atomicAdd(&s_cnt, __popcll(m));     \
        basew = __shfl(basew, 0);                                       \
        if (p) {                                                        \
            int pos = basew + __popcll(m & ((1ull << lane) - 1ull));    \
            if (pos < WCAP) {                                           \
                s_k[pos] = k_##k;                                       \
                s_b4[pos] = boxes4[0xFFFFFFFFu - (unsigned int)k_##k];  \
            }                                                           \
        }                                                               \
    }
    FOR_K(COMPACT_K)
#undef COMPACT_K
    __syncthreads();

    const int wcnt = s_cnt;
    const bool overflow = (wcnt > WCAP);  // pathological ties only

    // ---- Phase D1: parallel rank sort of the window (threads 0..wcnt).
    // rank_i = #{j : key_j > key_i}; keys unique -> permutation. Broadcast
    // LDS reads, conflict-free.
    if (!overflow && tid < wcnt) {
        const unsigned long long mykey = s_k[tid];
        const float4 mybox = s_b4[tid];
        int rank = 0;
        for (int j = 0; j < wcnt; ++j) rank += (s_k[j] > mykey) ? 1 : 0;
        s_ks[rank] = mykey;
        s_bs[rank] = mybox;
    }
    __syncthreads();

    // ---- Phase D2: parallel suppression bit-matrix. Task t = (row,chunk):
    // lane computes iou_gt(row, chunk*64+lane); one ballot per task; all 16
    // waves work concurrently. Row = selected-box role (reference op order).
    if (!overflow) {
        const int ntask = 2 * wcnt;
        for (int t = wave; t < ntask; t += NWAVES) {
            const int row = t >> 1, ch = t & 1;
            float4 rb = s_bs[row];
            float area_r =
                __fmul_rn(__fsub_rn(rb.z, rb.x), __fsub_rn(rb.w, rb.y));
            int colj = ch * 64 + lane;
            bool s = (colj < wcnt) &&
                     iou_gt(rb.x, rb.y, rb.z, rb.w, area_r, s_bs[colj]);
            unsigned long long m = __ballot(s);
            if (lane == 0) s_mask[row][ch] = m;
        }
    }
    __syncthreads();

    // ---- Phase D3: serial resolve (wave 0, all lanes lockstep; pure
    // bit-ops + one broadcast ds_read_b128 per kept box).
    if (wave == 0 && !overflow) {
        unsigned long long a0, a1;
        if (wcnt >= 64) {
            a0 = ~0ull;
            a1 = (wcnt >= 128) ? ~0ull
                               : ((wcnt > 64) ? ((1ull << (wcnt - 64)) - 1)
                                              : 0ull);
        } else {
            a0 = (wcnt > 0) ? ((1ull << wcnt) - 1) : 0ull;
            a1 = 0ull;
        }
        int nkept = 0;
        while ((a0 | a1) != 0 && nkept < MAX_BOXES) {
            int pos = a0 ? __builtin_ctzll(a0)
                         : 64 + __builtin_ctzll(a1);
            if (lane == 0)
                s_out[nkept] =
                    (int)(0xFFFFFFFFu - (unsigned int)s_ks[pos]);
            ++nkept;
            ulonglong2 m = *(const ulonglong2*)&s_mask[pos][0];
            a0 &= ~m.x;
            a1 &= ~m.y;
            // insurance vs infinite loop (self-IoU is 1 > T, but be safe):
            if (pos < 64) a0 &= ~(1ull << pos);
            else a1 &= ~(1ull << (pos - 64));
        }
        if (lane == 0) s_nsel = nkept;
    }
    __syncthreads();

    // ---- Phase E: exact fallback (window exhausted early / overflow).
    // Invariant: if !overflow and nsel0 < 20, every window member was
    // examined (kept or suppressed) -> all dead; non-members re-checked
    // against the selected set. Never triggers on typical data.
    const int nsel0 = s_nsel;
    const bool needs_more =
        (nsel0 < MAX_BOXES) && (overflow || (wcnt < s_total));
    if (needs_more) {
#define LIVE_K(k)                                                        \
        if (k_##k != 0) {                                                \
            bool dead =                                                  \
                (!overflow &&                                            \
                 ((unsigned int)(k_##k >> 32) >= tbits));                \
            if (!dead && nsel0 > 0) {                                    \
                int i = tid + (k)*NT;                                    \
                float4 bi = boxes4[i];                                   \
                for (int j = 0; j < nsel0; ++j) {                        \
                    float4 sb = boxes4[s_out[j]];                        \
                    float aj = __fmul_rn(__fsub_rn(sb.z, sb.x),          \
                                         __fsub_rn(sb.w, sb.y));         \
                    if (iou_gt(sb.x, sb.y, sb.z, sb.w, aj, bi)) {        \
                        dead = true;                                     \
                        break;                                           \
                    }                                                    \
                }                                                        \
            }                                                            \
            if (dead) k_##k = 0;                                         \
        }
        FOR_K(LIVE_K)
#undef LIVE_K
        for (int slot = nsel0; slot < MAX_BOXES; ++slot) {
            unsigned long long bk = 0;
#define MAXK_K(k) if (k_##k > bk) bk = k_##k;
            FOR_K(MAXK_K)
#undef MAXK_K
            #pragma unroll
            for (int off = 32; off >= 1; off >>= 1) {
                unsigned long long o =
                    (unsigned long long)__shfl_xor((long long)bk, off);
                if (o > bk) bk = o;
            }
            const int par = slot & 1;
            if (lane == 0) s_rk[par][wave] = bk;
            __syncthreads();
            unsigned long long f = s_rk[par][0];
            #pragma unroll
            for (int w = 1; w < NWAVES; ++w) {
                unsigned long long o = s_rk[par][w];
                if (o > f) f = o;
            }
            if (f == 0) break;  // uniform
            const int widx = (int)(0xFFFFFFFFu - (unsigned int)f);
            if (tid == 0) s_out[slot] = widx;
            float4 wb = boxes4[widx];  // uniform L1 broadcast
            const float area_j =
                __fmul_rn(__fsub_rn(wb.z, wb.x), __fsub_rn(wb.w, wb.y));
#define SCANE_K(k)                                                      \
            if (k_##k != 0) {                                           \
                int i = tid + (k)*NT;                                   \
                float4 b = boxes4[i];                                   \
                if (i == widx ||                                        \
                    iou_gt(wb.x, wb.y, wb.z, wb.w, area_j, b))          \
                    k_##k = 0;                                          \
            }
            FOR_K(SCANE_K)
#undef SCANE_K
        }
    }

    // ---- emit rows ----
    __syncthreads();
    if (tid < MAX_BOXES) {
        int bi = s_out[tid];
        int o = OUT_OFF_NMS + c * MAX_BOXES * 3 + tid * 3;
        if (bi >= 0) {
            out[o + 0] = 0.0f;
            out[o + 1] = (float)c;
            out[o + 2] = (float)bi;
        } else {
            out[o + 0] = -1.0f;
            out[o + 1] = -1.0f;
            out[o + 2] = -1.0f;
        }
    }
}

extern "C" void kernel_launch(void* const* d_in, const int* in_sizes, int n_in,
                              void* d_out, int out_size, void* d_ws,
                              size_t ws_size, hipStream_t stream) {
    const float* boxes = (const float*)d_in[0];   // [N,4] fp32
    const float* scores = (const float*)d_in[1];  // [N,C] fp32
    float* out = (float*)d_out;

    // Launch 1: coalesced transpose (+ boxes copy) into out.
    transpose_copy_kernel<<<K1_BLOCKS, NT, 0, stream>>>(boxes, scores, out);
    // Launch 2: NMS reads the transposed columns contiguously.
    nms_kernel<<<NUM_CLASSES, NT, 0, stream>>>(boxes, out);
}